// Round 5
// baseline (41.663 us; speedup 1.0000x reference)
//
#include <hip/hip_runtime.h>

#define MROWS 512
#define NCOLS 8192
#define NVALS 4096
#define BLOCK 512
#define NW 8
#define EPSF 1e-10f

typedef unsigned int u32;
typedef unsigned long long u64;

// transposed layout: logical e -> phys; thread t owns logical 8t..8t+7 at phys (i<<9)+t (conflict-free)
__device__ __forceinline__ int TP(int e) { return ((e & 7) << 9) | (e >> 3); }

__global__ __launch_bounds__(BLOCK, 4) void listmle_fused(
    const float* __restrict__ outputs,
    const float* __restrict__ runtime,
    const int*   __restrict__ idxs,
    u64* __restrict__ gacc,        // [0]=fixed-point sum, [1]=done counter (memset 0 per call)
    float* __restrict__ out)
{
    __shared__ u32 A[NVALS];       // minidx -> bucket cursors -> bucket exp-totals -> excl bucket sums
    __shared__ u32 C[NVALS + 8];   // bucket counts -> exclusive bases (TP); C[NVALS] = K sentinel
    __shared__ u64 KA[NVALS];      // (cmpkey<<32)|exp_bits, compacted per bucket
    __shared__ float s_max[NW], s_ps[NW], s_fs[NW], s_lg[NW];
    __shared__ u32 s_cnt[NW];

    const int tid = threadIdx.x, lane = tid & 63, wave = tid >> 6;
    const int row = blockIdx.x;
    const float* rp = outputs + (size_t)row * NCOLS;
    const float* rr = runtime + (size_t)row * NCOLS;
    const int*   ri = idxs    + (size_t)row * NCOLS;

    // ---- P0: load 16 items/thread; column j(m) = (m>>2)*2048 + tid*4 + (m&3) ----
    int vidx[16]; float vrt[16], vpred[16];
    #pragma unroll
    for (int q = 0; q < 4; ++q) {
        const int b0 = (q << 11) + (tid << 2);
        int4   i4 = *reinterpret_cast<const int4*>(ri + b0);
        float4 r4 = *reinterpret_cast<const float4*>(rr + b0);
        float4 p4 = *reinterpret_cast<const float4*>(rp + b0);
        vidx[q*4+0]=i4.x;  vidx[q*4+1]=i4.y;  vidx[q*4+2]=i4.z;  vidx[q*4+3]=i4.w;
        vrt [q*4+0]=r4.x;  vrt [q*4+1]=r4.y;  vrt [q*4+2]=r4.z;  vrt [q*4+3]=r4.w;
        vpred[q*4+0]=p4.x; vpred[q*4+1]=p4.y; vpred[q*4+2]=p4.z; vpred[q*4+3]=p4.w;
    }
    #pragma unroll
    for (int i = 0; i < 8; ++i) { A[(i<<9)+tid] = 0xFFFFFFFFu; C[(i<<9)+tid] = 0u; }
    if (tid < 8) C[NVALS + tid] = 0u;
    __syncthreads();                                    // B1

    // ---- P1: dedup — first occurrence (min column) per value ----
    #pragma unroll
    for (int m = 0; m < 16; ++m) {
        const u32 j = ((m >> 2) << 11) + (tid << 2) + (m & 3);
        atomicMin(&A[vidx[m]], j);
    }
    __syncthreads();                                    // B2

    // ---- P2: kept mask; bucket counts; max over all preds; sum of kept preds ----
    float lmax = -INFINITY, psum = 0.f;
    u32 kept = 0;
    #pragma unroll
    for (int m = 0; m < 16; ++m) {
        lmax = fmaxf(lmax, vpred[m]);
        const u32 j = ((m >> 2) << 11) + (tid << 2) + (m & 3);
        if (A[vidx[m]] == j) {
            kept |= 1u << m;
            psum += vpred[m];
            u32 rt24 = (u32)(vrt[m] * 16777216.0f);     // exact monotone 24-bit key
            rt24 = rt24 > 0xFFFFFFu ? 0xFFFFFFu : rt24;
            atomicAdd(&C[TP((int)(rt24 >> 12))], 1u);
        }
    }
    #pragma unroll
    for (int off = 32; off > 0; off >>= 1) {
        lmax = fmaxf(lmax, __shfl_down(lmax, off));
        psum += __shfl_down(psum, off);
    }
    if (lane == 0) { s_max[wave] = lmax; s_ps[wave] = psum; }
    __syncthreads();                                    // B3

    float mx = s_max[0];
    #pragma unroll
    for (int w = 1; w < NW; ++w) mx = fmaxf(mx, s_max[w]);

    // ---- P3: count scan (8/thread, TP layout); zero bucket cursors (minidx dead) ----
    u32 c8[8], lsum = 0;
    #pragma unroll
    for (int i = 0; i < 8; ++i) { c8[i] = C[(i<<9)+tid]; lsum += c8[i]; }
    #pragma unroll
    for (int i = 0; i < 8; ++i) A[(i<<9)+tid] = 0u;
    u32 xs = lsum;
    #pragma unroll
    for (int off = 1; off < 64; off <<= 1) { u32 y = __shfl_up(xs, off); if (lane >= off) xs += y; }
    if (lane == 63) s_cnt[wave] = xs;
    __syncthreads();                                    // B4

    u32 run = xs - lsum, K = 0;
    #pragma unroll
    for (int w = 0; w < NW; ++w) { const u32 t = s_cnt[w]; if (w < wave) run += t; K += t; }
    #pragma unroll
    for (int i = 0; i < 8; ++i) { const u32 c = c8[i]; C[(i<<9)+tid] = run; run += c; }
    if (tid == 0) C[NVALS] = K;                         // sentinel base
    __syncthreads();                                    // B5

    // ---- P5: scatter (cmpkey|exp) by atomic arrival within bucket ----
    #pragma unroll
    for (int m = 0; m < 16; ++m) {
        if (kept & (1u << m)) {
            const u32 j = ((m >> 2) << 11) + (tid << 2) + (m & 3);
            u32 rt24 = (u32)(vrt[m] * 16777216.0f);
            rt24 = rt24 > 0xFFFFFFu ? 0xFFFFFFu : rt24;
            const int b = (int)(rt24 >> 12);
            const u32 base = C[TP(b)];
            const u32 ra = atomicAdd(&A[TP(b)], 1u);
            const u32 ck = ((rt24 & 0xFFFu) << 13) | j; // unique: (low12, column)
            const float e = __expf(vpred[m] - mx);
            KA[base + ra] = ((u64)ck << 32) | (u64)__float_as_uint(e);
        }
    }
    __syncthreads();                                    // B6

    // ---- P6: within-bucket inclusive prefix (double, order-insensitive at f32);
    //          max-key item writes bucket exp-total; empty buckets keep 0.0 (cursor=0) ----
    float pf[16];
    #pragma unroll
    for (int m = 0; m < 16; ++m) {
        if (kept & (1u << m)) {
            const u32 j = ((m >> 2) << 11) + (tid << 2) + (m & 3);
            u32 rt24 = (u32)(vrt[m] * 16777216.0f);
            rt24 = rt24 > 0xFFFFFFu ? 0xFFFFFFu : rt24;
            const int b = (int)(rt24 >> 12);
            const u32 base = C[TP(b)];
            const u32 lim  = (b == NVALS - 1) ? C[NVALS] : C[TP(b + 1)];
            const u32 ck = ((rt24 & 0xFFFu) << 13) | j;
            double dsm = 0.0, dall = 0.0;
            float eo = 0.f;
            u32 r = 0;
            for (u32 q = base; q < lim; ++q) {
                const u64 v = KA[q];
                const u32 k2 = (u32)(v >> 32);
                const float e2 = __uint_as_float((u32)v);
                dall += (double)e2;
                if (k2 < ck) { dsm += (double)e2; ++r; }
                else if (k2 == ck) eo = e2;
            }
            pf[m] = (float)(dsm + (double)eo);          // inclusive within-bucket prefix
            if (r == lim - base - 1)                    // unique max-key item per bucket
                A[TP(b)] = __float_as_uint((float)dall);
        }
    }
    __syncthreads();                                    // B7

    // ---- P7: exclusive float scan of 4096 bucket totals ----
    float f8[8], fsum = 0.f;
    #pragma unroll
    for (int i = 0; i < 8; ++i) { f8[i] = __uint_as_float(A[(i<<9)+tid]); fsum += f8[i]; }
    float xf = fsum;
    #pragma unroll
    for (int off = 1; off < 64; off <<= 1) { float y = __shfl_up(xf, off); if (lane >= off) xf += y; }
    if (lane == 63) s_fs[wave] = xf;
    __syncthreads();                                    // B8

    float frun = xf - fsum;
    #pragma unroll
    for (int w = 0; w < NW; ++w) if (w < wave) frun += s_fs[w];
    #pragma unroll
    for (int i = 0; i < 8; ++i) { const float c = f8[i]; A[(i<<9)+tid] = __float_as_uint(frun); frun += c; }
    __syncthreads();                                    // B9

    // ---- P9: logs ----
    float logacc = 0.f;
    #pragma unroll
    for (int m = 0; m < 16; ++m) {
        if (kept & (1u << m)) {
            u32 rt24 = (u32)(vrt[m] * 16777216.0f);
            rt24 = rt24 > 0xFFFFFFu ? 0xFFFFFFu : rt24;
            const float S = __uint_as_float(A[TP((int)(rt24 >> 12))]);
            logacc += __logf(S + pf[m] + EPSF);
        }
    }
    #pragma unroll
    for (int off = 32; off > 0; off >>= 1) logacc += __shfl_down(logacc, off);
    if (lane == 0) s_lg[wave] = logacc;
    __syncthreads();                                    // B10

    // ---- fused finalize: exact fixed-point accumulation + last-block write ----
    if (tid == 0) {
        float lt = 0.f, pt = 0.f;
        #pragma unroll
        for (int w = 0; w < NW; ++w) { lt += s_lg[w]; pt += s_ps[w]; }
        const double rowval = (double)(lt - pt + (float)K * mx);
        const long long fx = __double2ll_rn(rowval * 1048576.0);
        atomicAdd(&gacc[0], (u64)fx);                   // exact integer adds: deterministic
        __threadfence();
        const u64 old = atomicAdd(&gacc[1], 1ull);
        if (old == (u64)(MROWS - 1)) {                  // last block finalizes
            __threadfence();
            const u64 tot = atomicAdd(&gacc[0], 0ull);  // coherent read via RMW
            out[0] = (float)(((double)(long long)tot) / (1048576.0 * (double)MROWS));
        }
    }
}

extern "C" void kernel_launch(void* const* d_in, const int* in_sizes, int n_in,
                              void* d_out, int out_size, void* d_ws, size_t ws_size,
                              hipStream_t stream) {
    const float* outputs = (const float*)d_in[0];
    const float* runtime = (const float*)d_in[1];
    const int*   idxs    = (const int*)d_in[2];
    float* out = (float*)d_out;
    u64*   acc = (u64*)d_ws;

    hipMemsetAsync(d_ws, 0, 16, stream);   // zero accumulator + done counter (graph-capturable)
    listmle_fused<<<MROWS, BLOCK, 0, stream>>>(outputs, runtime, idxs, acc, out);
}

// Round 6
// 31.332 us; speedup vs baseline: 1.3297x; 1.3297x over previous
//
#include <hip/hip_runtime.h>

#define MROWS 512
#define NCOLS 8192
#define NVALS 4096
#define BLOCK 512
#define NW 8
#define EPSF 1e-10f

typedef unsigned int u32;
typedef unsigned long long u64;

// transposed layout: thread t owns logical e=8t..8t+7 at phys (i<<9)+t (conflict-free)
__device__ __forceinline__ int TP(int e) { return ((e & 7) << 9) | (e >> 3); }

__global__ __launch_bounds__(BLOCK, 4) void listmle_row_kernel(
    const float* __restrict__ outputs,
    const float* __restrict__ runtime,
    const int*   __restrict__ idxs,
    float* __restrict__ row_out)
{
    __shared__ u32 A[NVALS];       // minidx -> bucket cursors -> bucket totals -> excl bucket sums
    __shared__ u32 C[NVALS + 8];   // bucket counts -> exclusive bases (TP); C[NVALS] = K sentinel
    __shared__ u64 KA[NVALS];      // (cmpkey<<32)|exp_bits, compacted per bucket (arrival order)
    __shared__ float s_max[NW], s_ps[NW], s_fs[NW], s_lg[NW];
    __shared__ u32 s_cnt[NW];

    const int tid = threadIdx.x, lane = tid & 63, wave = tid >> 6;
    const int row = blockIdx.x;
    const float* rp = outputs + (size_t)row * NCOLS;
    const float* rr = runtime + (size_t)row * NCOLS;
    const int*   ri = idxs    + (size_t)row * NCOLS;

    // ---- P0: load 16 items/thread; column j(m) = (m>>2)*2048 + tid*4 + (m&3) ----
    int vidx[16]; float vrt[16], vpred[16];
    #pragma unroll
    for (int q = 0; q < 4; ++q) {
        const int b0 = (q << 11) + (tid << 2);
        int4   i4 = *reinterpret_cast<const int4*>(ri + b0);
        float4 r4 = *reinterpret_cast<const float4*>(rr + b0);
        float4 p4 = *reinterpret_cast<const float4*>(rp + b0);
        vidx[q*4+0]=i4.x;  vidx[q*4+1]=i4.y;  vidx[q*4+2]=i4.z;  vidx[q*4+3]=i4.w;
        vrt [q*4+0]=r4.x;  vrt [q*4+1]=r4.y;  vrt [q*4+2]=r4.z;  vrt [q*4+3]=r4.w;
        vpred[q*4+0]=p4.x; vpred[q*4+1]=p4.y; vpred[q*4+2]=p4.z; vpred[q*4+3]=p4.w;
    }
    #pragma unroll
    for (int i = 0; i < 8; ++i) { A[(i<<9)+tid] = 0xFFFFFFFFu; C[(i<<9)+tid] = 0u; }
    if (tid < 8) C[NVALS + tid] = 0u;
    __syncthreads();                                    // B1

    // ---- P1: dedup — first occurrence (min column) per value ----
    #pragma unroll
    for (int m = 0; m < 16; ++m) {
        const u32 j = ((m >> 2) << 11) + (tid << 2) + (m & 3);
        atomicMin(&A[vidx[m]], j);
    }
    __syncthreads();                                    // B2

    // ---- P2: kept mask; 24-bit keys to regs; bucket counts; max of all preds; sum kept preds ----
    u32 vkey[16];
    float lmax = -INFINITY, psum = 0.f;
    u32 kept = 0;
    #pragma unroll
    for (int m = 0; m < 16; ++m) {
        lmax = fmaxf(lmax, vpred[m]);
        u32 rt24 = (u32)(vrt[m] * 16777216.0f);         // exact monotone 24-bit key
        rt24 = rt24 > 0xFFFFFFu ? 0xFFFFFFu : rt24;
        vkey[m] = rt24;
        const u32 j = ((m >> 2) << 11) + (tid << 2) + (m & 3);
        if (A[vidx[m]] == j) {
            kept |= 1u << m;
            psum += vpred[m];
            atomicAdd(&C[TP((int)(rt24 >> 12))], 1u);
        }
    }
    #pragma unroll
    for (int off = 32; off > 0; off >>= 1) {
        lmax = fmaxf(lmax, __shfl_down(lmax, off));
        psum += __shfl_down(psum, off);
    }
    if (lane == 0) { s_max[wave] = lmax; s_ps[wave] = psum; }
    __syncthreads();                                    // B3

    float mx = s_max[0];
    #pragma unroll
    for (int w = 1; w < NW; ++w) mx = fmaxf(mx, s_max[w]);

    // ---- P3: exclusive scan of 4096 bucket counts (8/thread, TP); zero cursors (minidx dead) ----
    u32 c8[8], lsum = 0;
    #pragma unroll
    for (int i = 0; i < 8; ++i) { c8[i] = C[(i<<9)+tid]; lsum += c8[i]; }
    #pragma unroll
    for (int i = 0; i < 8; ++i) A[(i<<9)+tid] = 0u;
    u32 xs = lsum;
    #pragma unroll
    for (int off = 1; off < 64; off <<= 1) { u32 y = __shfl_up(xs, off); if (lane >= off) xs += y; }
    if (lane == 63) s_cnt[wave] = xs;
    __syncthreads();                                    // B4

    u32 run = xs - lsum, K = 0;
    #pragma unroll
    for (int w = 0; w < NW; ++w) { const u32 t = s_cnt[w]; if (w < wave) run += t; K += t; }
    #pragma unroll
    for (int i = 0; i < 8; ++i) { const u32 c = c8[i]; C[(i<<9)+tid] = run; run += c; }
    if (tid == 0) C[NVALS] = K;                         // sentinel base
    __syncthreads();                                    // B5

    // ---- P5: scatter (cmpkey|exp) by atomic arrival within bucket ----
    #pragma unroll
    for (int m = 0; m < 16; ++m) {
        if (kept & (1u << m)) {
            const u32 j = ((m >> 2) << 11) + (tid << 2) + (m & 3);
            const u32 rt24 = vkey[m];
            const int b = (int)(rt24 >> 12);
            const u32 base = C[TP(b)];
            const u32 ra = atomicAdd(&A[TP(b)], 1u);
            const u32 ck = ((rt24 & 0xFFFu) << 13) | j; // unique: (low12, column)
            const float e = __expf(vpred[m] - mx);
            KA[base + ra] = ((u64)ck << 32) | (u64)__float_as_uint(e);
        }
    }
    __syncthreads();                                    // B6

    // ---- P6: within-bucket inclusive prefix (double accum: order-insensitive at f32);
    //          max-key item (rank == cnt-1) writes bucket total = its own inclusive prefix ----
    float pf[16];
    #pragma unroll
    for (int m = 0; m < 16; ++m) {
        if (kept & (1u << m)) {
            const u32 j = ((m >> 2) << 11) + (tid << 2) + (m & 3);
            const u32 rt24 = vkey[m];
            const int b = (int)(rt24 >> 12);
            const u32 base = C[TP(b)];
            const u32 lim  = (b == NVALS - 1) ? C[NVALS] : C[TP(b + 1)];
            const u32 ck = ((rt24 & 0xFFFu) << 13) | j;
            double dsm = 0.0;
            u32 r = 0;
            for (u32 q = base; q < lim; ++q) {
                const u64 v = KA[q];
                if ((u32)(v >> 32) < ck) { dsm += (double)__uint_as_float((u32)v); ++r; }
            }
            const float pfm = (float)(dsm + (double)__expf(vpred[m] - mx));
            pf[m] = pfm;
            if (r == lim - base - 1)                    // unique max-key item per bucket
                A[TP(b)] = __float_as_uint(pfm);        // empty buckets keep cursor 0 = 0.0f
        }
    }
    __syncthreads();                                    // B7

    // ---- P7: exclusive float scan of 4096 bucket totals ----
    float f8[8], fsum = 0.f;
    #pragma unroll
    for (int i = 0; i < 8; ++i) { f8[i] = __uint_as_float(A[(i<<9)+tid]); fsum += f8[i]; }
    float xf = fsum;
    #pragma unroll
    for (int off = 1; off < 64; off <<= 1) { float y = __shfl_up(xf, off); if (lane >= off) xf += y; }
    if (lane == 63) s_fs[wave] = xf;
    __syncthreads();                                    // B8

    float frun = xf - fsum;
    #pragma unroll
    for (int w = 0; w < NW; ++w) if (w < wave) frun += s_fs[w];
    #pragma unroll
    for (int i = 0; i < 8; ++i) { const float c = f8[i]; A[(i<<9)+tid] = __float_as_uint(frun); frun += c; }
    __syncthreads();                                    // B9

    // ---- P9: logs: inclusive global prefix = S_excl[bucket] + pf ----
    float logacc = 0.f;
    #pragma unroll
    for (int m = 0; m < 16; ++m) {
        if (kept & (1u << m)) {
            const float S = __uint_as_float(A[TP((int)(vkey[m] >> 12))]);
            logacc += __logf(S + pf[m] + EPSF);
        }
    }
    #pragma unroll
    for (int off = 32; off > 0; off >>= 1) logacc += __shfl_down(logacc, off);
    if (lane == 0) s_lg[wave] = logacc;
    __syncthreads();                                    // B10

    if (tid == 0) {
        float lt = 0.f, pt = 0.f;
        #pragma unroll
        for (int w = 0; w < NW; ++w) { lt += s_lg[w]; pt += s_ps[w]; }
        row_out[row] = lt - pt + (float)K * mx;
    }
}

__global__ __launch_bounds__(256) void listmle_finalize(
    const float* __restrict__ row_out, float* __restrict__ out)
{
    __shared__ double red_d[4];
    const int tid = threadIdx.x;
    const int lane = tid & 63, wave = tid >> 6;
    double acc = 0.0;
    for (int r = tid; r < MROWS; r += 256) acc += (double)row_out[r];
    #pragma unroll
    for (int off = 32; off > 0; off >>= 1) acc += __shfl_down(acc, off);
    if (lane == 0) red_d[wave] = acc;
    __syncthreads();
    if (tid == 0) {
        double tot = 0.0;
        for (int w = 0; w < 4; ++w) tot += red_d[w];
        out[0] = (float)(tot / (double)MROWS);
    }
}

extern "C" void kernel_launch(void* const* d_in, const int* in_sizes, int n_in,
                              void* d_out, int out_size, void* d_ws, size_t ws_size,
                              hipStream_t stream) {
    const float* outputs = (const float*)d_in[0];
    const float* runtime = (const float*)d_in[1];
    const int*   idxs    = (const int*)d_in[2];
    float* out = (float*)d_out;
    float* ws  = (float*)d_ws;

    listmle_row_kernel<<<MROWS, BLOCK, 0, stream>>>(outputs, runtime, idxs, ws);
    listmle_finalize<<<1, 256, 0, stream>>>(ws, out);
}